// Round 7
// baseline (6312.056 us; speedup 1.0000x reference)
//
#include <hip/hip_runtime.h>
#include <stdint.h>

#define B_    256
#define T_    160
#define DIN_  40
#define H_    768
#define NG_   3072
#define KP0_  1024     // [x 0..40 | pad | Wh 64..832 | pad to 1024]
#define HOFF0_ 64
#define KP12_ 1536     // [Wi(hin) 0..768 | Wh(own) 768..1536]
#define XC_   64       // padded x columns
#define NSTEP_ (T_ + 2)
#define ZP_   3328     // 64*52 floats per zred partial (pad 52: 16B-aligned, <=2-way banks)
#define BH_   ((size_t)B_ * H_)

typedef _Float16 f16;
typedef _Float16 half8 __attribute__((ext_vector_type(8)));
typedef float f32x4 __attribute__((ext_vector_type(4)));

#define AS1C(p) ((const __attribute__((address_space(1))) uint32_t*)(p))
#define AS3(p)  ((__attribute__((address_space(3))) uint32_t*)(p))

struct Params {
  const f16* wt0; const f16* wt1; const f16* wt2;
  const float* bq; const f16* x16;
  f16* hs0; f16* hs1; f16* hs2;
  float* cst; unsigned* cnt; float* out;
};

__device__ __forceinline__ float sigmoid_f(float x) { return 1.f / (1.f + __expf(-x)); }
__device__ __forceinline__ float tanh_f(float x) {
  x = fminf(15.f, fmaxf(-15.f, x));
  float e = __expf(2.f * x);
  return (e - 1.f) / (e + 1.f);
}

// Weights -> fp16, transposed [n'][k], gate-interleaved cols n' = 4*j + g.
__global__ void conv_w(const float* __restrict__ Wi, const float* __restrict__ Wh,
                       int in_dim, int hoff, int Kp, f16* __restrict__ dst) {
  __shared__ f16 tile[64][66];
  const int k0 = blockIdx.x * 64;
  const int by = blockIdx.y;            // 0..47
  const int g = by / 12, j0 = (by % 12) * 64;
  const int tid = threadIdx.x;
  #pragma unroll
  for (int it = 0; it < 16; ++it) {
    int idx = it * 256 + tid;
    int jj = idx & 63;
    int kk = idx >> 6;
    int k = k0 + kk;
    int oc = g * H_ + j0 + jj;
    float v = 0.f;
    if (k < in_dim) v = Wi[(size_t)k * NG_ + oc];
    else if (k >= hoff && k < hoff + H_) v = Wh[(size_t)(k - hoff) * NG_ + oc];
    tile[kk][jj] = (f16)v;
  }
  __syncthreads();
  #pragma unroll
  for (int it = 0; it < 16; ++it) {
    int idx = it * 256 + tid;
    int kk = idx & 63;
    int jj = idx >> 6;
    int np = 4 * (j0 + jj) + g;
    dst[(size_t)np * Kp + k0 + kk] = tile[kk][jj];
  }
}

__global__ void conv_b(const float* __restrict__ b0, const float* __restrict__ b1,
                       const float* __restrict__ b2, float* __restrict__ bq) {
  int id = blockIdx.x * 256 + threadIdx.x;
  if (id < 3 * NG_) {
    int l = id / NG_, np = id % NG_;
    int j = np >> 2, g = np & 3;
    const float* s = (l == 0) ? b0 : (l == 1 ? b1 : b2);
    bq[id] = s[g * H_ + j];
  }
}

// x [B,T,40] fp32 -> x16 [T,B,64] fp16 (cols 40..63 zero)
__global__ void conv_x(const float* __restrict__ x, f16* __restrict__ x16) {
  int id = blockIdx.x * 256 + threadIdx.x;
  if (id >= T_ * B_ * XC_) return;
  int k = id & 63;
  int b = (id >> 6) % B_;
  int t = id / (XC_ * B_);
  float v = (k < DIN_) ? x[((size_t)b * T_ + t) * DIN_ + k] : 0.f;
  x16[id] = (f16)v;
}

__global__ __launch_bounds__(512, 2) void lstm_fused(Params p) {
  __shared__ __align__(16) f16 Abuf[64 * 768];      // 96 KB: one 64-row H tile
  __shared__ __align__(16) f16 Xbuf[64 * 64];       // 8 KB : x tile
  __shared__ __align__(16) float zred[4 * ZP_];     // 52 KB: 4 merged k-partials

  const int tid = threadIdx.x;
  const int lane = tid & 63;
  const int w = tid >> 6;                  // 0..7 (k-eighth)
  const int bid = blockIdx.x;
  const int group = bid >> 6;              // 0..3 (64-batch tile), contiguous bids
  const int ntile = bid & 63;              // 0..63 (48 gate cols)
  const int n0 = ntile * 48;
  const int b0 = group * 64;
  unsigned* flg = p.cnt + (size_t)group * 2048;   // 64 flags x 128B

  // ---- persistent weights for L1/L2 (hin + own): 36 half8 = 144 VGPRs
  half8 b1h[9], b1o[9], b2h[9], b2o[9];
  #pragma unroll
  for (int ct = 0; ct < 3; ++ct)
    #pragma unroll
    for (int kt = 0; kt < 3; ++kt) {
      const size_t col = (size_t)(n0 + ct * 16 + (lane & 15));
      const int ko = w * 96 + kt * 32 + (lane >> 4) * 8;
      b1h[ct * 3 + kt] = *(const half8*)(p.wt1 + col * KP12_ + ko);
      b1o[ct * 3 + kt] = *(const half8*)(p.wt1 + col * KP12_ + 768 + ko);
      b2h[ct * 3 + kt] = *(const half8*)(p.wt2 + col * KP12_ + ko);
      b2o[ct * 3 + kt] = *(const half8*)(p.wt2 + col * KP12_ + 768 + ko);
    }

  // gate item: thread tid<384 owns (row, jp): 8 gate cols = 2 h cols
  const int grow = tid / 6, gjp = tid - grow * 6;
  const int gb = b0 + grow;
  const int ghc = ntile * 12 + 2 * gjp;
  float oa0 = 0.f, oa1 = 0.f;

  f32x4 acc[4][3];

  auto zero_acc = [&]() {
    #pragma unroll
    for (int rt = 0; rt < 4; ++rt)
      #pragma unroll
      for (int ct = 0; ct < 3; ++ct)
        acc[rt][ct] = (f32x4){0.f, 0.f, 0.f, 0.f};
  };

  auto mfma_A = [&](const half8 (&Bf)[9]) {
    #pragma unroll
    for (int kt = 0; kt < 3; ++kt) {
      const int chunk = w * 12 + kt * 4 + (lane >> 4);
      half8 a[4];
      #pragma unroll
      for (int rt = 0; rt < 4; ++rt) {
        const int row = rt * 16 + (lane & 15);
        a[rt] = *(const half8*)((const char*)Abuf + (size_t)row * 1536 +
                                (size_t)(chunk ^ (row & 7)) * 16);
      }
      #pragma unroll
      for (int ct = 0; ct < 3; ++ct)
        #pragma unroll
        for (int rt = 0; rt < 4; ++rt)
          acc[rt][ct] = __builtin_amdgcn_mfma_f32_16x16x32_f16(a[rt], Bf[ct * 3 + kt],
                                                               acc[rt][ct], 0, 0, 0);
    }
  };

  // waves 0-3 write partials, waves 4-7 merge-add -> 4 partials total
  auto zreduce = [&]() {
    if (w < 4) {
      float* zp = zred + (size_t)w * ZP_;
      #pragma unroll
      for (int rt = 0; rt < 4; ++rt)
        #pragma unroll
        for (int ct = 0; ct < 3; ++ct)
          #pragma unroll
          for (int r4 = 0; r4 < 4; ++r4)
            zp[(rt * 16 + (lane >> 4) * 4 + r4) * 52 + ct * 16 + (lane & 15)] = acc[rt][ct][r4];
    }
    __syncthreads();
    if (w >= 4) {
      float* zp = zred + (size_t)(w & 3) * ZP_;
      #pragma unroll
      for (int rt = 0; rt < 4; ++rt)
        #pragma unroll
        for (int ct = 0; ct < 3; ++ct)
          #pragma unroll
          for (int r4 = 0; r4 < 4; ++r4)
            zp[(rt * 16 + (lane >> 4) * 4 + r4) * 52 + ct * 16 + (lane & 15)] += acc[rt][ct][r4];
    }
    __syncthreads();
  };

  auto stage_H = [&](const f16* hs, int slot) {
    const size_t sb = (size_t)slot * BH_;
    #pragma unroll
    for (int i = 0; i < 12; ++i) {
      const int idx = w * 768 + i * 64 + lane;
      const int row = idx / 96;
      const int c = idx - row * 96;
      const int cg = c ^ (row & 7);
      const f16* src = hs + sb + (size_t)(b0 + row) * H_ + cg * 8;
      __builtin_amdgcn_global_load_lds(AS1C(src), AS3(Abuf + (size_t)(w * 768 + i * 64) * 8), 16, 0, 0);
    }
  };
  auto stage_X = [&](int t) {
    const int row = tid >> 3, c = tid & 7;
    const int cg = c ^ (row & 7);
    const f16* src = p.x16 + ((size_t)t * B_ + b0 + row) * XC_ + cg * 8;
    __builtin_amdgcn_global_load_lds(AS1C(src), AS3(Xbuf + (size_t)(w * 64) * 8), 16, 0, 0);
  };

  auto gates = [&](int l, int t, f16* hs, int slot, bool domean) {
    const float* z = zred + grow * 52 + gjp * 8;
    f32x4 za = *(const f32x4*)z + *(const f32x4*)(z + ZP_) +
               *(const f32x4*)(z + 2 * ZP_) + *(const f32x4*)(z + 3 * ZP_);
    f32x4 zb = *(const f32x4*)(z + 4) + *(const f32x4*)(z + 4 + ZP_) +
               *(const f32x4*)(z + 4 + 2 * ZP_) + *(const f32x4*)(z + 4 + 3 * ZP_);
    const float* bp = p.bq + l * NG_ + n0 + gjp * 8;
    za += *(const f32x4*)bp;
    zb += *(const f32x4*)(bp + 4);
    float* cp = p.cst + ((size_t)l * B_ + gb) * H_ + ghc;
    float c0 = 0.f, c1 = 0.f;
    if (t > 0) { c0 = cp[0]; c1 = cp[1]; }
    float i0 = sigmoid_f(za[0]), f0 = sigmoid_f(za[1]), g0 = tanh_f(za[2]), o0 = sigmoid_f(za[3]);
    float i1 = sigmoid_f(zb[0]), f1 = sigmoid_f(zb[1]), g1 = tanh_f(zb[2]), o1 = sigmoid_f(zb[3]);
    float cn0 = f0 * c0 + i0 * g0;
    float cn1 = f1 * c1 + i1 * g1;
    cp[0] = cn0; cp[1] = cn1;
    float h0 = o0 * tanh_f(cn0);
    float h1 = o1 * tanh_f(cn1);
    f16 hh0 = (f16)h0, hh1 = (f16)h1;
    unsigned u = ((unsigned)__builtin_bit_cast(uint16_t, hh1) << 16)
               |  (unsigned)__builtin_bit_cast(uint16_t, hh0);
    unsigned* hp = (unsigned*)(hs + (size_t)slot * BH_ + (size_t)gb * H_ + ghc);
    __hip_atomic_store(hp, u, __ATOMIC_RELAXED, __HIP_MEMORY_SCOPE_AGENT);
    if (domean) {
      oa0 += h0; oa1 += h1;
      if (t == T_ - 1) {
        p.out[(size_t)gb * H_ + ghc]     = oa0 * (1.f / T_);
        p.out[(size_t)gb * H_ + ghc + 1] = oa1 * (1.f / T_);
      }
    }
  };

  // ---- pipelined step loop: L0@t=s, L1@t=s-1, L2@t=s-2
  for (int s = 0; s < NSTEP_; ++s) {
    const int t0 = s, t1 = s - 1, t2 = s - 2;
    const bool a0 = (t0 < T_);
    const bool a1 = (t1 >= 0) && (t1 < T_);
    const bool a2 = (t2 >= 0) && (t2 < T_);

    // S1: stage H0 = h0[s-1] (slot s) and X(t0)
    stage_H(p.hs0, s > T_ ? T_ : s);
    stage_X(t0 < T_ ? t0 : T_ - 1);
    asm volatile("s_waitcnt vmcnt(0)" ::: "memory");
    __syncthreads();

    // M1: accL0 = W0x·X (wave 0) + W0h·H0 (streamed from L2)
    zero_acc();
    if (w == 0) {
      #pragma unroll
      for (int kt = 0; kt < 2; ++kt) {
        half8 bx[3];
        #pragma unroll
        for (int ct = 0; ct < 3; ++ct)
          bx[ct] = *(const half8*)(p.wt0 + (size_t)(n0 + ct * 16 + (lane & 15)) * KP0_ +
                                   kt * 32 + (lane >> 4) * 8);
        const int chunk = kt * 4 + (lane >> 4);
        half8 a[4];
        #pragma unroll
        for (int rt = 0; rt < 4; ++rt) {
          const int row = rt * 16 + (lane & 15);
          a[rt] = *(const half8*)((const char*)Xbuf + (size_t)row * 128 +
                                  (size_t)(chunk ^ (row & 7)) * 16);
        }
        #pragma unroll
        for (int ct = 0; ct < 3; ++ct)
          #pragma unroll
          for (int rt = 0; rt < 4; ++rt)
            acc[rt][ct] = __builtin_amdgcn_mfma_f32_16x16x32_f16(a[rt], bx[ct], acc[rt][ct], 0, 0, 0);
      }
    }
    #pragma unroll
    for (int kt = 0; kt < 3; ++kt) {
      half8 bh[3];
      #pragma unroll
      for (int ct = 0; ct < 3; ++ct)
        bh[ct] = *(const half8*)(p.wt0 + (size_t)(n0 + ct * 16 + (lane & 15)) * KP0_ +
                                 HOFF0_ + w * 96 + kt * 32 + (lane >> 4) * 8);
      const int chunk = w * 12 + kt * 4 + (lane >> 4);
      half8 a[4];
      #pragma unroll
      for (int rt = 0; rt < 4; ++rt) {
        const int row = rt * 16 + (lane & 15);
        a[rt] = *(const half8*)((const char*)Abuf + (size_t)row * 1536 +
                                (size_t)(chunk ^ (row & 7)) * 16);
      }
      #pragma unroll
      for (int ct = 0; ct < 3; ++ct)
        #pragma unroll
        for (int rt = 0; rt < 4; ++rt)
          acc[rt][ct] = __builtin_amdgcn_mfma_f32_16x16x32_f16(a[rt], bh[ct], acc[rt][ct], 0, 0, 0);
    }
    zreduce();

    // M2: accL1 = W1hin·H0 (persistent)
    zero_acc();
    mfma_A(b1h);
    __syncthreads();                       // M2 ds_reads done -> Abuf free

    // S2: stage H1 = h1[s-2] (slot s-1); G0: gates L0 (reads zred-L0)
    stage_H(p.hs1, t1 < 0 ? 0 : s - 1);
    if (a0 && tid < 384) gates(0, t0, p.hs0, s + 1, false);
    asm volatile("s_waitcnt vmcnt(0)" ::: "memory");
    __syncthreads();

    // M3: accL1 += W1own·H1
    mfma_A(b1o);
    zreduce();

    // M4: accL2 = W2hin·H1
    zero_acc();
    mfma_A(b2h);
    __syncthreads();                       // Abuf free

    // S3: stage H2 = h2[s-3] (slot s-2); G1: gates L1
    stage_H(p.hs2, t2 < 0 ? 0 : s - 2);
    if (a1 && tid < 384) gates(1, t1, p.hs1, s, false);
    asm volatile("s_waitcnt vmcnt(0)" ::: "memory");
    __syncthreads();

    // M5: accL2 += W2own·H2
    mfma_A(b2o);
    zreduce();

    // G2: gates L2 (+mean accumulation)
    if (a2 && tid < 384) gates(2, t2, p.hs2, s - 1, true);
    asm volatile("s_waitcnt vmcnt(0)" ::: "memory");
    __syncthreads();

    // distributed group barrier: 64 flags, wave 7 polls one flag per lane
    if (w == 7) {
      if (lane == 0)
        __hip_atomic_store(flg + (size_t)ntile * 32, (unsigned)(s + 1),
                           __ATOMIC_RELAXED, __HIP_MEMORY_SCOPE_AGENT);
      unsigned* fp = flg + (size_t)lane * 32;
      for (;;) {
        unsigned v = __hip_atomic_load(fp, __ATOMIC_RELAXED, __HIP_MEMORY_SCOPE_AGENT);
        if (__ballot(v >= (unsigned)(s + 1)) == ~0ull) break;
        __builtin_amdgcn_s_sleep(1);
      }
    }
    __syncthreads();
  }
}

extern "C" void kernel_launch(void* const* d_in, const int* in_sizes, int n_in,
                              void* d_out, int out_size, void* d_ws, size_t ws_size,
                              hipStream_t stream) {
  const float* x   = (const float*)d_in[0];
  const float* Wi0 = (const float*)d_in[1];
  const float* Wh0 = (const float*)d_in[2];
  const float* b0  = (const float*)d_in[3];
  const float* Wi1 = (const float*)d_in[4];
  const float* Wh1 = (const float*)d_in[5];
  const float* b1  = (const float*)d_in[6];
  const float* Wi2 = (const float*)d_in[7];
  const float* Wh2 = (const float*)d_in[8];
  const float* b2  = (const float*)d_in[9];

  char* wsb = (char*)d_ws;
  size_t off = 0;
  auto nxt = [&](size_t sz) { char* p = wsb + off; off += (sz + 255) & ~(size_t)255; return p; };
  f16*      wt0  = (f16*)nxt((size_t)NG_ * KP0_ * 2);          // 6.3 MB
  f16*      wt1  = (f16*)nxt((size_t)NG_ * KP12_ * 2);         // 9.4 MB
  f16*      wt2  = (f16*)nxt((size_t)NG_ * KP12_ * 2);         // 9.4 MB
  float*    bq   = (float*)nxt((size_t)3 * NG_ * 4);
  f16*      x16  = (f16*)nxt((size_t)T_ * B_ * XC_ * 2);       // 5.2 MB
  f16*      hs0  = (f16*)nxt((size_t)(T_ + 1) * B_ * H_ * 2);  // 63.3 MB
  f16*      hs1  = (f16*)nxt((size_t)(T_ + 1) * B_ * H_ * 2);
  f16*      hs2  = (f16*)nxt((size_t)(T_ + 1) * B_ * H_ * 2);
  float*    cst  = (float*)nxt((size_t)3 * B_ * H_ * 4);       // 2.4 MB
  unsigned* cnt  = (unsigned*)nxt(4 * 64 * 128);               // 4 groups x 64 flags x 128B
  if (off > ws_size) return;  // insufficient workspace

  const size_t slot_bytes = (size_t)B_ * H_ * 2;
  hipMemsetAsync(hs0, 0, slot_bytes, stream);
  hipMemsetAsync(hs1, 0, slot_bytes, stream);
  hipMemsetAsync(hs2, 0, slot_bytes, stream);
  hipMemsetAsync(cnt, 0, 4 * 64 * 128, stream);

  hipLaunchKernelGGL(conv_w, dim3(KP0_ / 64, 48), dim3(256), 0, stream, Wi0, Wh0, DIN_, HOFF0_, KP0_, wt0);
  hipLaunchKernelGGL(conv_w, dim3(KP12_ / 64, 48), dim3(256), 0, stream, Wi1, Wh1, H_, H_, KP12_, wt1);
  hipLaunchKernelGGL(conv_w, dim3(KP12_ / 64, 48), dim3(256), 0, stream, Wi2, Wh2, H_, H_, KP12_, wt2);
  hipLaunchKernelGGL(conv_b, dim3((3 * NG_ + 255) / 256), dim3(256), 0, stream, b0, b1, b2, bq);
  hipLaunchKernelGGL(conv_x, dim3((T_ * B_ * XC_ + 255) / 256), dim3(256), 0, stream, x, x16);

  Params prm{wt0, wt1, wt2, bq, x16, hs0, hs1, hs2, cst, cnt, (float*)d_out};
  hipLaunchKernelGGL(lstm_fused, dim3(256), dim3(512), 0, stream, prm);
}